// Round 3
// baseline (43.469 us; speedup 1.0000x reference)
//
#include <hip/hip_runtime.h>
#include <math.h>

#define D_IN  2048
#define D_OUT 8192

// One wave (64 threads) per row. Element-bit assignment:
//   FWHT-2048: e = r2 | lane<<2 | j<<8   (r2: bits 0-1 in float4 comps, lane: bits 2-7, j: bits 8-10, j<8)
//   FWHT-8192: o = r2 | lane<<2 | c<<8   (c: bits 8-12, c<32)
// Stages run in ascending h (reference association): h=1,2 on r2; h=4..128 via
// __shfl_xor masks 1..32; h>=256 on j/c register pairs. All butterflies are
// exact (lo+hi, lo-hi); shfl form fmaf(+-1, mine, partner) is the same fp op.

__global__ __launch_bounds__(64, 2) void fastfood_kernel(
    const float* __restrict__ xg, const float* __restrict__ Bg,
    const float* __restrict__ Gg, const float* __restrict__ Sg,
    const int*   __restrict__ Pg, const float* __restrict__ Ug,
    float* __restrict__ outg)
{
  __shared__ float4 a4s[D_IN / 4];   // 8 KB: FWHT-2048 result (linear layout)

  const int lane = threadIdx.x;      // 0..63
  const int row  = blockIdx.x;

  // ================= FWHT-2048 of B*x (reg + shfl only) =================
  float a[32];
  {
    const float4* x4 = reinterpret_cast<const float4*>(xg + (size_t)row * D_IN);
    const float4* B4 = reinterpret_cast<const float4*>(Bg);
#pragma unroll
    for (int j = 0; j < 8; ++j) {
      float4 xv = x4[lane + 64 * j];
      float4 bv = B4[lane + 64 * j];
      a[4 * j + 0] = xv.x * bv.x; a[4 * j + 1] = xv.y * bv.y;
      a[4 * j + 2] = xv.z * bv.z; a[4 * j + 3] = xv.w * bv.w;
    }
  }
  // h=1 (bit0), h=2 (bit1): radix-4 within each float4 group, exact association
#pragma unroll
  for (int j = 0; j < 8; ++j) {
    float x0 = a[4 * j], x1 = a[4 * j + 1], x2 = a[4 * j + 2], x3 = a[4 * j + 3];
    float y0 = x0 + x1, y1 = x0 - x1, y2 = x2 + x3, y3 = x2 - x3;   // h=1
    a[4 * j + 0] = y0 + y2; a[4 * j + 2] = y0 - y2;                 // h=2
    a[4 * j + 1] = y1 + y3; a[4 * j + 3] = y1 - y3;
  }
  // h=4..128: lane bits 0..5
#pragma unroll
  for (int m = 1; m <= 32; m <<= 1) {
    float sgn = (lane & m) ? -1.0f : 1.0f;
#pragma unroll
    for (int k = 0; k < 32; ++k) {
      float p = __shfl_xor(a[k], m, 64);
      a[k] = fmaf(sgn, a[k], p);    // set: partner - mine ; clear: mine + partner
    }
  }
  // h=256,512,1024: j bits 0..2
#pragma unroll
  for (int hb = 1; hb < 8; hb <<= 1)
#pragma unroll
    for (int j = 0; j < 8; ++j)
      if (!(j & hb))
#pragma unroll
        for (int r2 = 0; r2 < 4; ++r2) {
          float lo = a[4 * j + r2], hi = a[4 * (j | hb) + r2];
          a[4 * j + r2] = lo + hi; a[4 * (j | hb) + r2] = lo - hi;
        }
  // store to LDS (linear; per-instr 64 consecutive float4 -> conflict-free)
#pragma unroll
  for (int j = 0; j < 8; ++j)
    a4s[lane + 64 * j] = make_float4(a[4 * j], a[4 * j + 1], a[4 * j + 2], a[4 * j + 3]);
  __syncthreads();

  // ================= gather + Gaussian scale =================
  float v[128];
  {
    const float* a_f = reinterpret_cast<const float*>(a4s);
    const int4*   P4 = reinterpret_cast<const int4*>(Pg);
    const float4* G4 = reinterpret_cast<const float4*>(Gg);
#pragma unroll
    for (int c = 0; c < 32; ++c) {
      int4   pp = P4[lane + 64 * c];
      float4 gv = G4[lane + 64 * c];
      v[4 * c + 0] = a_f[pp.x & (D_IN - 1)] * gv.x;
      v[4 * c + 1] = a_f[pp.y & (D_IN - 1)] * gv.y;
      v[4 * c + 2] = a_f[pp.z & (D_IN - 1)] * gv.z;
      v[4 * c + 3] = a_f[pp.w & (D_IN - 1)] * gv.w;
    }
  }

  // ================= FWHT-8192 (reg + shfl only) =================
  // h=1,2: r2 bits
#pragma unroll
  for (int c = 0; c < 32; ++c) {
    float x0 = v[4 * c], x1 = v[4 * c + 1], x2 = v[4 * c + 2], x3 = v[4 * c + 3];
    float y0 = x0 + x1, y1 = x0 - x1, y2 = x2 + x3, y3 = x2 - x3;
    v[4 * c + 0] = y0 + y2; v[4 * c + 2] = y0 - y2;
    v[4 * c + 1] = y1 + y3; v[4 * c + 3] = y1 - y3;
  }
  // h=4..128: lane bits
#pragma unroll
  for (int m = 1; m <= 32; m <<= 1) {
    float sgn = (lane & m) ? -1.0f : 1.0f;
#pragma unroll
    for (int k = 0; k < 128; ++k) {
      float p = __shfl_xor(v[k], m, 64);
      v[k] = fmaf(sgn, v[k], p);
    }
  }
  // h=256..4096: c bits 0..4
#pragma unroll
  for (int hb = 1; hb < 32; hb <<= 1)
#pragma unroll
    for (int c = 0; c < 32; ++c)
      if (!(c & hb))
#pragma unroll
        for (int r2 = 0; r2 < 4; ++r2) {
          float lo = v[4 * c + r2], hi = v[4 * (c | hb) + r2];
          v[4 * c + r2] = lo + hi; v[4 * (c | hb) + r2] = lo - hi;
        }

  // ================= epilogue =================
  {
    const float c1 = (float)(1.0 / (6.283185307179586 * 90.50966799187809)); // 1/(2*pi*sqrt(8192))
    const float4* S4 = reinterpret_cast<const float4*>(Sg);
    const float4* U4 = reinterpret_cast<const float4*>(Ug);
    float4* out4 = reinterpret_cast<float4*>(outg + (size_t)row * D_OUT);
#pragma unroll
    for (int c = 0; c < 32; ++c) {
      int o4 = lane + 64 * c;
      float4 s4 = S4[o4], u4 = U4[o4];
      float4 res;
      float rev;
      rev = fmaf(v[4 * c + 0] * s4.x, c1, u4.x); rev -= rintf(rev);
      res.x = __builtin_amdgcn_cosf(rev) * 0.015625f;
      rev = fmaf(v[4 * c + 1] * s4.y, c1, u4.y); rev -= rintf(rev);
      res.y = __builtin_amdgcn_cosf(rev) * 0.015625f;
      rev = fmaf(v[4 * c + 2] * s4.z, c1, u4.z); rev -= rintf(rev);
      res.z = __builtin_amdgcn_cosf(rev) * 0.015625f;
      rev = fmaf(v[4 * c + 3] * s4.w, c1, u4.w); rev -= rintf(rev);
      res.w = __builtin_amdgcn_cosf(rev) * 0.015625f;
      out4[o4] = res;
    }
  }
}

extern "C" void kernel_launch(void* const* d_in, const int* in_sizes, int n_in,
                              void* d_out, int out_size, void* d_ws, size_t ws_size,
                              hipStream_t stream) {
  const float* x = (const float*)d_in[0];
  const float* B = (const float*)d_in[1];
  const float* G = (const float*)d_in[2];
  const float* S = (const float*)d_in[3];
  const int*   P = (const int*)d_in[4];
  const float* U = (const float*)d_in[5];
  float* out = (float*)d_out;
  const int rows = in_sizes[0] / D_IN;  // 2048
  fastfood_kernel<<<rows, 64, 0, stream>>>(x, B, G, S, P, U, out);
}

// Round 5
// 40.345 us; speedup vs baseline: 1.0774x; 1.0774x over previous
//
#include <hip/hip_runtime.h>
#include <math.h>

#define D_IN  2048
#define D_OUT 8192

// All cross-lane butterflies on the VALU pipe (DPP / permlane_swap), keeping the
// DS pipe for: a-store (4xb128), random permutation gather (64xb32), and one
// cross-wave half-exchange (32xb128). Stage order is globally ascending h with
// exact reference association (lo+hi / lo-hi, single rounding each).
//
// DPP direction convention (GCN): row_ror:N => dst[i] = src[(i-N) mod 16]
// (data moves toward higher lanes; classic DPP reductions end in lane 63).

#if __has_builtin(__builtin_amdgcn_permlane16_swap) && __has_builtin(__builtin_amdgcn_permlane32_swap)
#define HAVE_PLSWAP 1
#endif

template<int CTRL>
__device__ __forceinline__ float dpp_full(float x) {
  int xi = __float_as_int(x);
  return __int_as_float(__builtin_amdgcn_update_dpp(xi, xi, CTRL, 0xF, 0xF, true));
}
// partner value across lane-xor-4:
//   lanes with bit2=1 (banks 1,3): dst[i]=src[i-4]        -> row_ror:4
//   lanes with bit2=0 (banks 0,2): dst[i]=src[(i+4)%16]   -> row_ror:12
__device__ __forceinline__ float dpp_xor4(float x) {
  int xi = __float_as_int(x);
  int r = __builtin_amdgcn_update_dpp(0, xi, 0x124, 0xF, 0xA, false);  // ror:4  -> banks 1,3
  r     = __builtin_amdgcn_update_dpp(r,  xi, 0x12C, 0xF, 0x5, false); // ror:12 -> banks 0,2
  return __int_as_float(r);
}

// exact butterfly across lane-xor-16 for a pair of independent values
__device__ __forceinline__ void bfly_pl16(float& A, float& B, float sgn) {
#ifdef HAVE_PLSWAP
  auto r0 = __builtin_amdgcn_permlane16_swap(__float_as_uint(A), __float_as_uint(B), false, false);
  float lo = __uint_as_float(r0[0]), hi = __uint_as_float(r0[1]);
  float s = lo + hi, d = lo - hi;
  auto r1 = __builtin_amdgcn_permlane16_swap(__float_as_uint(s), __float_as_uint(d), false, false);
  A = __uint_as_float(r1[0]); B = __uint_as_float(r1[1]);
  (void)sgn;
#else
  float pA = __shfl_xor(A, 16, 64); A = fmaf(sgn, A, pA);
  float pB = __shfl_xor(B, 16, 64); B = fmaf(sgn, B, pB);
#endif
}
__device__ __forceinline__ void bfly_pl32(float& A, float& B, float sgn) {
#ifdef HAVE_PLSWAP
  auto r0 = __builtin_amdgcn_permlane32_swap(__float_as_uint(A), __float_as_uint(B), false, false);
  float lo = __uint_as_float(r0[0]), hi = __uint_as_float(r0[1]);
  float s = lo + hi, d = lo - hi;
  auto r1 = __builtin_amdgcn_permlane32_swap(__float_as_uint(s), __float_as_uint(d), false, false);
  A = __uint_as_float(r1[0]); B = __uint_as_float(r1[1]);
  (void)sgn;
#else
  float pA = __shfl_xor(A, 32, 64); A = fmaf(sgn, A, pA);
  float pB = __shfl_xor(B, 32, 64); B = fmaf(sgn, B, pB);
#endif
}

__global__ __launch_bounds__(128, 2) void fastfood_kernel(
    const float* __restrict__ xg, const float* __restrict__ Bg,
    const float* __restrict__ Gg, const float* __restrict__ Sg,
    const int*   __restrict__ Pg, const float* __restrict__ Ug,
    float* __restrict__ outg)
{
  __shared__ float4 A4s[D_IN / 4];   // 8 KB: FWHT-2048 result (linear)
  __shared__ float4 X4s[4096 / 4];   // 16 KB: cross-wave exchange buffer

  const int t = threadIdx.x, lane = t & 63, wave = t >> 6, row = blockIdx.x;
  const float sg1  = (lane & 1)  ? -1.f : 1.f;
  const float sg2  = (lane & 2)  ? -1.f : 1.f;
  const float sg4  = (lane & 4)  ? -1.f : 1.f;
  const float sg8  = (lane & 8)  ? -1.f : 1.f;
  const float sg16 = (lane & 16) ? -1.f : 1.f;
  const float sg32 = (lane & 32) ? -1.f : 1.f;

  // ===== FWHT-2048 of B*x — fully in registers, redundantly per wave =====
  // element d = c(bits0-1) | lane<<2 | j<<8  (j = quad 0..7)
  float a[32];
  {
    const float4* x4 = reinterpret_cast<const float4*>(xg + (size_t)row * D_IN);
    const float4* B4 = reinterpret_cast<const float4*>(Bg);
#pragma unroll
    for (int j = 0; j < 8; ++j) {
      float4 xv = x4[lane + 64 * j], bv = B4[lane + 64 * j];
      a[4*j+0] = xv.x * bv.x; a[4*j+1] = xv.y * bv.y;
      a[4*j+2] = xv.z * bv.z; a[4*j+3] = xv.w * bv.w;
    }
  }
#pragma unroll
  for (int j = 0; j < 8; ++j) {                                  // h=1,2
    float x0=a[4*j],x1=a[4*j+1],x2=a[4*j+2],x3=a[4*j+3];
    float y0=x0+x1,y1=x0-x1,y2=x2+x3,y3=x2-x3;
    a[4*j]=y0+y2; a[4*j+2]=y0-y2; a[4*j+1]=y1+y3; a[4*j+3]=y1-y3;
  }
#pragma unroll
  for (int k = 0; k < 32; ++k) { float p = dpp_full<0xB1>(a[k]);  a[k] = fmaf(sg1, a[k], p); }  // h=4
#pragma unroll
  for (int k = 0; k < 32; ++k) { float p = dpp_full<0x4E>(a[k]);  a[k] = fmaf(sg2, a[k], p); }  // h=8
#pragma unroll
  for (int k = 0; k < 32; ++k) { float p = dpp_xor4(a[k]);        a[k] = fmaf(sg4, a[k], p); }  // h=16
#pragma unroll
  for (int k = 0; k < 32; ++k) { float p = dpp_full<0x128>(a[k]); a[k] = fmaf(sg8, a[k], p); }  // h=32
#pragma unroll
  for (int k = 0; k < 32; k += 2) bfly_pl16(a[k], a[k+1], sg16);                                // h=64
#pragma unroll
  for (int k = 0; k < 32; k += 2) bfly_pl32(a[k], a[k+1], sg32);                                // h=128
#pragma unroll
  for (int b = 1; b < 8; b <<= 1)                                                               // h=256..1024
#pragma unroll
    for (int j = 0; j < 8; ++j) if (!(j & b))
#pragma unroll
      for (int c = 0; c < 4; ++c) {
        float lo = a[4*j+c], hi = a[4*(j|b)+c];
        a[4*j+c] = lo + hi; a[4*(j|b)+c] = lo - hi;
      }
  // each wave stores one half (both hold identical data)
#pragma unroll
  for (int jj = 0; jj < 4; ++jj) {
    int j = 4 * wave + jj;
    A4s[lane + 64 * j] = make_float4(a[4*j], a[4*j+1], a[4*j+2], a[4*j+3]);
  }
  __syncthreads();   // #1

  // ===== gather + Gaussian scale =====
  // o = c | lane<<2 | q<<8 | wave<<12   (q = 0..15)
  float v[64];
  {
    const float* a_f = reinterpret_cast<const float*>(A4s);
    const int4*   P4 = reinterpret_cast<const int4*>(Pg);
    const float4* G4 = reinterpret_cast<const float4*>(Gg);
#pragma unroll
    for (int q = 0; q < 16; ++q) {
      int idx = lane + 64 * q + 1024 * wave;
      int4 pp = P4[idx]; float4 gv = G4[idx];
      v[4*q+0] = a_f[pp.x & (D_IN-1)] * gv.x;
      v[4*q+1] = a_f[pp.y & (D_IN-1)] * gv.y;
      v[4*q+2] = a_f[pp.z & (D_IN-1)] * gv.z;
      v[4*q+3] = a_f[pp.w & (D_IN-1)] * gv.w;
    }
  }

  // ===== FWHT-8192: h=1..2048 all in-wave =====
#pragma unroll
  for (int q = 0; q < 16; ++q) {                                 // h=1,2
    float x0=v[4*q],x1=v[4*q+1],x2=v[4*q+2],x3=v[4*q+3];
    float y0=x0+x1,y1=x0-x1,y2=x2+x3,y3=x2-x3;
    v[4*q]=y0+y2; v[4*q+2]=y0-y2; v[4*q+1]=y1+y3; v[4*q+3]=y1-y3;
  }
#pragma unroll
  for (int k = 0; k < 64; ++k) { float p = dpp_full<0xB1>(v[k]);  v[k] = fmaf(sg1, v[k], p); }  // h=4
#pragma unroll
  for (int k = 0; k < 64; ++k) { float p = dpp_full<0x4E>(v[k]);  v[k] = fmaf(sg2, v[k], p); }  // h=8
#pragma unroll
  for (int k = 0; k < 64; ++k) { float p = dpp_xor4(v[k]);        v[k] = fmaf(sg4, v[k], p); }  // h=16
#pragma unroll
  for (int k = 0; k < 64; ++k) { float p = dpp_full<0x128>(v[k]); v[k] = fmaf(sg8, v[k], p); }  // h=32
#pragma unroll
  for (int k = 0; k < 64; k += 2) bfly_pl16(v[k], v[k+1], sg16);                                // h=64
#pragma unroll
  for (int k = 0; k < 64; k += 2) bfly_pl32(v[k], v[k+1], sg32);                                // h=128
#pragma unroll
  for (int b = 1; b < 16; b <<= 1)                                                              // h=256..2048
#pragma unroll
    for (int q = 0; q < 16; ++q) if (!(q & b))
#pragma unroll
      for (int c = 0; c < 4; ++c) {
        float lo = v[4*q+c], hi = v[4*(q|b)+c];
        v[4*q+c] = lo + hi; v[4*(q|b)+c] = lo - hi;
      }

  // ===== h=4096 across the two waves via LDS half-exchange =====
  if (wave == 1) {
#pragma unroll
    for (int q = 0; q < 16; ++q) {
      int Q = (lane & 31) + (q << 5) + ((lane >> 5) << 9);
      X4s[Q] = make_float4(v[4*q], v[4*q+1], v[4*q+2], v[4*q+3]);
    }
  }
  __syncthreads();   // #2
  if (wave == 0) {
#pragma unroll
    for (int q = 0; q < 16; ++q) {
      int Q = (lane & 31) + (q << 5) + ((lane >> 5) << 9);
      float4 h4 = X4s[Q];
      float s0 = v[4*q+0] + h4.x, d0 = v[4*q+0] - h4.x;
      float s1 = v[4*q+1] + h4.y, d1 = v[4*q+1] - h4.y;
      float s2 = v[4*q+2] + h4.z, d2 = v[4*q+2] - h4.z;
      float s3 = v[4*q+3] + h4.w, d3 = v[4*q+3] - h4.w;
      X4s[Q] = make_float4(d0, d1, d2, d3);
      v[4*q+0]=s0; v[4*q+1]=s1; v[4*q+2]=s2; v[4*q+3]=s3;
    }
  }
  __syncthreads();   // #3
  if (wave == 1) {
#pragma unroll
    for (int q = 0; q < 16; ++q) {
      int Q = (lane & 31) + (q << 5) + ((lane >> 5) << 9);
      float4 d4 = X4s[Q];
      v[4*q+0]=d4.x; v[4*q+1]=d4.y; v[4*q+2]=d4.z; v[4*q+3]=d4.w;
    }
  }

  // ===== epilogue: cos(Vx + 2*pi*U) * sqrt(2/O) =====
  {
    const float c1 = (float)(1.0 / (6.283185307179586 * 90.50966799187808)); // 1/(2*pi*sqrt(8192))
    const float4* S4 = reinterpret_cast<const float4*>(Sg);
    const float4* U4 = reinterpret_cast<const float4*>(Ug);
    float4* out4 = reinterpret_cast<float4*>(outg + (size_t)row * D_OUT);
#pragma unroll
    for (int q = 0; q < 16; ++q) {
      int idx = lane + 64 * q + 1024 * wave;
      float4 s4 = S4[idx], u4 = U4[idx], res;
      float rev;
      rev = fmaf(v[4*q+0]*s4.x, c1, u4.x); rev -= rintf(rev); res.x = __builtin_amdgcn_cosf(rev) * 0.015625f;
      rev = fmaf(v[4*q+1]*s4.y, c1, u4.y); rev -= rintf(rev); res.y = __builtin_amdgcn_cosf(rev) * 0.015625f;
      rev = fmaf(v[4*q+2]*s4.z, c1, u4.z); rev -= rintf(rev); res.z = __builtin_amdgcn_cosf(rev) * 0.015625f;
      rev = fmaf(v[4*q+3]*s4.w, c1, u4.w); rev -= rintf(rev); res.w = __builtin_amdgcn_cosf(rev) * 0.015625f;
      out4[idx] = res;
    }
  }
}

extern "C" void kernel_launch(void* const* d_in, const int* in_sizes, int n_in,
                              void* d_out, int out_size, void* d_ws, size_t ws_size,
                              hipStream_t stream) {
  const float* x = (const float*)d_in[0];
  const float* B = (const float*)d_in[1];
  const float* G = (const float*)d_in[2];
  const float* S = (const float*)d_in[3];
  const int*   P = (const int*)d_in[4];
  const float* U = (const float*)d_in[5];
  float* out = (float*)d_out;
  const int rows = in_sizes[0] / D_IN;  // 2048
  fastfood_kernel<<<rows, 128, 0, stream>>>(x, B, G, S, P, U, out);
}